// Round 2
// baseline (3986.988 us; speedup 1.0000x reference)
//
#include <hip/hip_runtime.h>
#include <hip/hip_bf16.h>
#include <stdint.h>

#define H 180
#define W 180
#define HW 32400
#define CIN 256
#define NB 4
#define NCLS 10
#define NPROP 200

// ---- workspace layout ----
// Phase 1 (conv1 -> conv2): x buffer occupies [0, 132,710,400).
// Phase 2 (post-conv2):     x is dead; all small buffers ALIAS into the x
// region (stream order makes this safe). Total ws requirement = 132.7 MB.
#define OFF_X      0ULL             // conv1 output x: 4*256*180*180 f32 = 132,710,400 B
#define OFF_NMS    0ULL             // nms heatmap: 4*10*32400 f32 = 5,184,000 B
#define OFF_HIST   5184000ULL       // 4*4096 int = 65,536 B
#define OFF_CNT    5249536ULL       // 4 int
#define OFF_CAND   5249568ULL       // 4*4096 u64 = 131,072 B
#define OFF_BSEL   5380640ULL       // 4 int
#define OFF_TPOS   5380672ULL       // 4*200 int
#define OFF_TLAB   5383872ULL       // 4*200 int
#define WS_NEEDED  132710400ULL

__device__ __forceinline__ float sigm(float v) { return 1.0f / (1.0f + expf(-v)); }

// ---------------- conv1 (3x3, 256->256) + BN + ReLU ----------------
// grid (3, 45, 16=b*4+cotile), block 256
// block tile: 64 co x (4 rows x 64 cols); per-thread 8co x 8cols (one row)
__global__ __launch_bounds__(256, 3)
void conv1_bn_relu(const float* __restrict__ in, const float* __restrict__ wgt,
                   const float* __restrict__ gamma, const float* __restrict__ beta,
                   const float* __restrict__ mean, const float* __restrict__ var,
                   float* __restrict__ xout)
{
    __shared__ float s_in[8][6][68];   // [ci][row][col], stride 68 -> <=2-way bank conflict
    __shared__ float s_w[64][73];      // [co][ci*9+tap], 72 used (+1 pad)
    const int bx = blockIdx.x, by = blockIdx.y, bz = blockIdx.z;
    const int b = bz >> 2, co0 = (bz & 3) * 64;
    const int row0 = by * 4, col0 = bx * 64;
    const int tid = threadIdx.x;
    const int tc = tid >> 5;           // 0..7: co group (8 co each)
    const int ts = tid & 31;
    const int trow = ts >> 3;          // 0..3
    const int csub = (ts & 7) * 8;     // 0..56

    float acc[8][8];
    #pragma unroll
    for (int i = 0; i < 8; ++i)
        #pragma unroll
        for (int j = 0; j < 8; ++j) acc[i][j] = 0.f;

    for (int ci0 = 0; ci0 < CIN; ci0 += 8) {
        __syncthreads();
        // stage input: 8 ci x 6 rows x 66 cols (halo included), zero-padded OOB
        for (int l = tid; l < 8*6*66; l += 256) {
            int ci = l / 396, rem = l % 396;
            int r = rem / 66, c = rem % 66;
            int gy = row0 - 1 + r, gx = col0 - 1 + c;
            float v = 0.f;
            if ((unsigned)gy < (unsigned)H && (unsigned)gx < (unsigned)W)
                v = in[(((size_t)b*CIN + ci0 + ci)*H + gy)*W + gx];
            s_in[ci][r][c] = v;
        }
        // stage weights: 64 co x (8ci*9tap contiguous in OIHW)
        for (int l = tid; l < 64*72; l += 256) {
            int co = l / 72, k = l % 72;
            s_w[co][k] = wgt[((size_t)(co0+co)*CIN + ci0)*9 + k];
        }
        __syncthreads();
        #pragma unroll
        for (int ci = 0; ci < 8; ++ci) {
            #pragma unroll
            for (int dy = 0; dy < 3; ++dy) {
                float iv[10];
                #pragma unroll
                for (int t = 0; t < 10; ++t) iv[t] = s_in[ci][trow+dy][csub + t];
                #pragma unroll
                for (int dx = 0; dx < 3; ++dx) {
                    float wv[8];
                    #pragma unroll
                    for (int k = 0; k < 8; ++k) wv[k] = s_w[tc*8 + k][ci*9 + dy*3 + dx];
                    #pragma unroll
                    for (int k = 0; k < 8; ++k)
                        #pragma unroll
                        for (int j = 0; j < 8; ++j)
                            acc[k][j] = fmaf(wv[k], iv[j+dx], acc[k][j]);
                }
            }
        }
    }
    const int y = row0 + trow;
    #pragma unroll
    for (int k = 0; k < 8; ++k) {
        int co = co0 + tc*8 + k;
        float sc = gamma[co] / sqrtf(var[co] + 1e-5f);
        float sh = beta[co] - mean[co] * sc;
        #pragma unroll
        for (int j = 0; j < 8; ++j) {
            int x = col0 + csub + j;
            if (x < W) {
                float v = fmaf(acc[k][j], sc, sh);
                xout[(((size_t)b*CIN + co)*H + y)*W + x] = fmaxf(v, 0.f);
            }
        }
    }
}

// ---------------- conv2 (3x3, 256->10) + bias ----------------
// grid (3, 45, 4), block 256; tile 10co x (4 rows x 64 cols); thread = 1 pixel, 10 co
__global__ __launch_bounds__(256, 3)
void conv2_bias(const float* __restrict__ x, const float* __restrict__ wgt,
                const float* __restrict__ bias, float* __restrict__ dense)
{
    __shared__ float s_in[16][6][68];
    __shared__ float s_w[16][9][12];   // [ci][tap][co], 10 used, 12 for 16B align
    const int bx = blockIdx.x, by = blockIdx.y, b = blockIdx.z;
    const int row0 = by * 4, col0 = bx * 64;
    const int tid = threadIdx.x;
    const int trow = tid >> 6, j = tid & 63;
    float acc[10];
    #pragma unroll
    for (int k = 0; k < 10; ++k) acc[k] = 0.f;

    for (int ci0 = 0; ci0 < CIN; ci0 += 16) {
        __syncthreads();
        for (int l = tid; l < 16*6*66; l += 256) {
            int ci = l / 396, rem = l % 396;
            int r = rem / 66, c = rem % 66;
            int gy = row0 - 1 + r, gx = col0 - 1 + c;
            float v = 0.f;
            if ((unsigned)gy < (unsigned)H && (unsigned)gx < (unsigned)W)
                v = x[(((size_t)b*CIN + ci0 + ci)*H + gy)*W + gx];
            s_in[ci][r][c] = v;
        }
        for (int l = tid; l < 10*16*9; l += 256) {
            int co = l / 144, k = l % 144;
            int ci = k / 9, tap = k % 9;
            s_w[ci][tap][co] = wgt[((size_t)co*CIN + ci0 + ci)*9 + tap];
        }
        __syncthreads();
        #pragma unroll
        for (int ci = 0; ci < 16; ++ci) {
            #pragma unroll
            for (int dy = 0; dy < 3; ++dy) {
                float iv[3];
                #pragma unroll
                for (int t = 0; t < 3; ++t) iv[t] = s_in[ci][trow+dy][j + t];
                #pragma unroll
                for (int dx = 0; dx < 3; ++dx) {
                    const float* wp = &s_w[ci][dy*3+dx][0];
                    float4 wa = *(const float4*)wp;
                    float4 wb = *(const float4*)(wp + 4);
                    float2 wc = *(const float2*)(wp + 8);
                    float ival = iv[dx];
                    acc[0] = fmaf(wa.x, ival, acc[0]);
                    acc[1] = fmaf(wa.y, ival, acc[1]);
                    acc[2] = fmaf(wa.z, ival, acc[2]);
                    acc[3] = fmaf(wa.w, ival, acc[3]);
                    acc[4] = fmaf(wb.x, ival, acc[4]);
                    acc[5] = fmaf(wb.y, ival, acc[5]);
                    acc[6] = fmaf(wb.z, ival, acc[6]);
                    acc[7] = fmaf(wb.w, ival, acc[7]);
                    acc[8] = fmaf(wc.x, ival, acc[8]);
                    acc[9] = fmaf(wc.y, ival, acc[9]);
                }
            }
        }
    }
    const int y = row0 + trow, xcol = col0 + j;
    if (xcol < W) {
        #pragma unroll
        for (int k = 0; k < 10; ++k)
            dense[(((size_t)b*NCLS + k)*H + y)*W + xcol] = acc[k] + bias[k];
    }
}

// ---------------- sigmoid + 3x3 NMS ----------------
// grid (40 = b*10+k, 180 rows), block 192
__global__ void nms_kernel(const float* __restrict__ dense, float* __restrict__ nms)
{
    const int x = threadIdx.x;
    if (x >= W) return;
    const int bk = blockIdx.x;
    const int y = blockIdx.y;
    const int k = bk % NCLS;
    const float* p = dense + (size_t)bk * HW;
    float c = sigm(p[y*W + x]);
    float outv;
    if (k >= 8) {
        outv = c;                                   // kernel-1 classes: identity
    } else if (x == 0 || x == W-1 || y == 0 || y == H-1) {
        outv = 0.f;                                 // border: local_max==0 != sigmoid>0
    } else {
        float m = c;
        #pragma unroll
        for (int dy = -1; dy <= 1; ++dy)
            #pragma unroll
            for (int dx = -1; dx <= 1; ++dx) {
                if (dy == 0 && dx == 0) continue;
                m = fmaxf(m, sigm(p[(y+dy)*W + (x+dx)]));
            }
        outv = (c == m) ? c : 0.f;
    }
    nms[(size_t)bk * HW + y*W + x] = outv;
}

// ---------------- per-batch histogram of positive nms values ----------------
// grid (32, 4=b), block 256
__global__ void hist_kernel(const float* __restrict__ nms, int* __restrict__ hist)
{
    __shared__ int h[4096];
    const int b = blockIdx.y;
    for (int l = threadIdx.x; l < 4096; l += 256) h[l] = 0;
    __syncthreads();
    const float* p = nms + (size_t)b * (NCLS*HW);
    for (int i = blockIdx.x*256 + threadIdx.x; i < NCLS*HW; i += gridDim.x*256) {
        float v = p[i];
        if (v > 0.f) {
            int bin = (int)(v * 4096.f);
            if (bin > 4095) bin = 4095;
            atomicAdd(&h[bin], 1);
        }
    }
    __syncthreads();
    for (int l = threadIdx.x; l < 4096; l += 256)
        if (h[l]) atomicAdd(&hist[b*4096 + l], h[l]);
}

// ---------------- find threshold bin: largest B with suffix_count(B) >= 200 ----
// grid 4, block 256
__global__ void scan_kernel(const int* __restrict__ hist, int* __restrict__ bsel)
{
    __shared__ int ss[256];
    const int b = blockIdx.x;
    const int t = threadIdx.x;
    const int base = 4096 - 16*(t+1);  // thread 0 owns the TOP 16 bins
    int s = 0;
    #pragma unroll
    for (int i = 0; i < 16; ++i) s += hist[b*4096 + base + i];
    ss[t] = s;
    __syncthreads();
    for (int off = 1; off < 256; off <<= 1) {
        int v = (t >= off) ? ss[t-off] : 0;
        __syncthreads();
        ss[t] += v;
        __syncthreads();
    }
    int incl = ss[t];
    int excl = incl - s;
    if (excl < NPROP && incl >= NPROP) {
        int acc = excl, bfound = base;
        for (int bin = base + 15; bin >= base; --bin) {
            acc += hist[b*4096 + bin];
            if (acc >= NPROP) { bfound = bin; break; }
        }
        bsel[b] = bfound;
    }
    if (t == 255 && ss[255] < NPROP) bsel[b] = 0;
}

// ---------------- collect candidates with bin >= bsel ----------------
// grid (64, 4=b), block 256
__global__ void collect_kernel(const float* __restrict__ nms, const int* __restrict__ bsel,
                               int* __restrict__ cnt, unsigned long long* __restrict__ cand)
{
    const int b = blockIdx.y;
    const int B0 = bsel[b];
    const float* p = nms + (size_t)b * (NCLS*HW);
    for (int i = blockIdx.x*256 + threadIdx.x; i < NCLS*HW; i += gridDim.x*256) {
        float v = p[i];
        if (v > 0.f) {
            int bin = (int)(v * 4096.f);
            if (bin > 4095) bin = 4095;
            if (bin >= B0) {
                int slot = atomicAdd(&cnt[b], 1);
                if (slot < 4096) {
                    unsigned int vb = __float_as_uint(v);
                    // ascending sort key = value DESC, index ASC (top_k tie-break)
                    cand[(size_t)b*4096 + slot] =
                        ((unsigned long long)(~vb) << 32) | (unsigned int)i;
                }
            }
        }
    }
}

// ---------------- bitonic sort 4096 + emit pos/labels/scores ----------------
// grid 4, block 1024
__global__ void sort_emit(const unsigned long long* __restrict__ cand, const int* __restrict__ cnt,
                          const float* __restrict__ nms, const float* __restrict__ bev_pos,
                          float* __restrict__ out, int* __restrict__ tpos, int* __restrict__ tlab)
{
    __shared__ unsigned long long key[4096];
    const int b = blockIdx.x;
    const int t = threadIdx.x;
    int n = cnt[b]; if (n > 4096) n = 4096;
    for (int l = t; l < 4096; l += 1024)
        key[l] = (l < n) ? cand[(size_t)b*4096 + l] : ~0ULL;
    __syncthreads();
    for (int k = 2; k <= 4096; k <<= 1) {
        for (int jj = k >> 1; jj > 0; jj >>= 1) {
            for (int l = t; l < 2048; l += 1024) {
                int i  = 2*l - (l & (jj-1));
                int ix = i + jj;
                bool up = ((i & k) == 0);
                unsigned long long a = key[i], c = key[ix];
                if ((a > c) == up) { key[i] = c; key[ix] = a; }
            }
            __syncthreads();
        }
    }
    for (int p = t; p < NPROP; p += 1024) {
        unsigned long long kk = key[p];
        unsigned int idx = (unsigned int)kk;   // flat index within batch: k*HW + pos
        if (idx >= (unsigned)(NCLS*HW)) idx = 0;   // pad-key safety (never hit in practice)
        int label = idx / HW;
        int pos   = idx % HW;
        out[206400 + b*NPROP + p] = (float)label;
        out[204800 + (b*NPROP + p)*2 + 0] = bev_pos[pos*2 + 0];
        out[204800 + (b*NPROP + p)*2 + 1] = bev_pos[pos*2 + 1];
        tpos[b*NPROP + p] = pos;
        tlab[b*NPROP + p] = label;
        #pragma unroll
        for (int k2 = 0; k2 < NCLS; ++k2)
            out[207200 + (b*NCLS + k2)*NPROP + p] = nms[((size_t)b*NCLS + k2)*HW + pos];
    }
}

// ---------------- query_feat gather: bev + class embed ----------------
// grid (256=c, 4=b), block 256 (200 active)
__global__ void feat_kernel(const float* __restrict__ bev, const float* __restrict__ cew,
                            const float* __restrict__ ceb, const int* __restrict__ tpos,
                            const int* __restrict__ tlab, float* __restrict__ out)
{
    const int c = blockIdx.x, b = blockIdx.y;
    const int t = threadIdx.x;
    if (t >= NPROP) return;
    int pos = tpos[b*NPROP + t];
    int lab = tlab[b*NPROP + t];
    float v = bev[((size_t)b*CIN + c)*HW + pos] + cew[c*NCLS + lab] + ceb[c];
    out[((size_t)b*CIN + c)*NPROP + t] = v;
}

extern "C" void kernel_launch(void* const* d_in, const int* in_sizes, int n_in,
                              void* d_out, int out_size, void* d_ws, size_t ws_size,
                              hipStream_t stream)
{
    const float* bev   = (const float*)d_in[0];
    const float* bpos  = (const float*)d_in[1];
    const float* w1    = (const float*)d_in[2];
    const float* gamma = (const float*)d_in[3];
    const float* beta  = (const float*)d_in[4];
    const float* mean  = (const float*)d_in[5];
    const float* var   = (const float*)d_in[6];
    const float* w2    = (const float*)d_in[7];
    const float* b2    = (const float*)d_in[8];
    const float* cew   = (const float*)d_in[9];
    const float* ceb   = (const float*)d_in[10];
    float* out = (float*)d_out;
    char* ws = (char*)d_ws;

    float* xbuf = (float*)(ws + OFF_X);
    float* nmsb = (float*)(ws + OFF_NMS);
    int* hist   = (int*)(ws + OFF_HIST);
    int* cnt    = (int*)(ws + OFF_CNT);
    unsigned long long* cand = (unsigned long long*)(ws + OFF_CAND);
    int* bsel   = (int*)(ws + OFF_BSEL);
    int* tpos   = (int*)(ws + OFF_TPOS);
    int* tlab   = (int*)(ws + OFF_TLAB);
    float* dense = out + 215200;   // dense_heatmap region of d_out

    // Phase 1: convs (x buffer owns the whole ws region)
    conv1_bn_relu<<<dim3(3, 45, 16), 256, 0, stream>>>(bev, w1, gamma, beta, mean, var, xbuf);
    conv2_bias  <<<dim3(3, 45, 4),  256, 0, stream>>>(xbuf, w2, b2, dense);
    // Phase 2: x is dead; small buffers alias into it (stream-ordered)
    hipMemsetAsync(ws + OFF_HIST, 0, 65536 + 32, stream);   // hist + cnt
    nms_kernel  <<<dim3(40, 180),   192, 0, stream>>>(dense, nmsb);
    hist_kernel <<<dim3(32, 4),     256, 0, stream>>>(nmsb, hist);
    scan_kernel <<<4,               256, 0, stream>>>(hist, bsel);
    collect_kernel<<<dim3(64, 4),   256, 0, stream>>>(nmsb, bsel, cnt, cand);
    sort_emit   <<<4,              1024, 0, stream>>>(cand, cnt, nmsb, bpos, out, tpos, tlab);
    feat_kernel <<<dim3(256, 4),    256, 0, stream>>>(bev, cew, ceb, tpos, tlab, out);
}

// Round 3
// 1105.060 us; speedup vs baseline: 3.6079x; 3.6079x over previous
//
#include <hip/hip_runtime.h>
#include <hip/hip_bf16.h>
#include <stdint.h>

#define H 180
#define W 180
#define HW 32400
#define CIN 256
#define NCLS 10
#define NPROP 200
#define WTAP 589824   // 9 taps * 32 cig * 256 co * 8 = elems per split-weight variant

// ---- workspace layout ----
// Phase 1 (conv1 -> conv2): x buffer owns [0, 132,710,400).
// Phase 2 (post-conv2): x dead; small buffers alias into it. ws need = 132.7 MB.
#define OFF_X      0ULL
#define OFF_NMS    0ULL
#define OFF_HIST   5184000ULL
#define OFF_CNT    5249536ULL
#define OFF_CAND   5249568ULL
#define OFF_BSEL   5380640ULL
#define OFF_TPOS   5380672ULL
#define OFF_TLAB   5383872ULL

typedef __attribute__((ext_vector_type(8))) short short8;
typedef __attribute__((ext_vector_type(4))) float f32x4;

__device__ __forceinline__ float sigm(float v) { return 1.0f / (1.0f + expf(-v)); }

__device__ __forceinline__ unsigned bfround(unsigned u) {
    return (u + 0x7FFFu + ((u >> 16) & 1u)) >> 16;
}
__device__ __forceinline__ void splitbf(float v, short &hi, short &lo) {
    unsigned u = __float_as_uint(v);
    unsigned hb = bfround(u);
    float fh = __uint_as_float(hb << 16);
    unsigned lb = bfround(__float_as_uint(v - fh));
    hi = (short)hb; lo = (short)lb;
}

// ---------------- weight split/reorder: OIHW f32 -> [tap][ci/8][co][8] bf16 hi|lo ----
__global__ void split_w_kernel(const float* __restrict__ w1, short* __restrict__ Wq)
{
    int idx = blockIdx.x * 256 + threadIdx.x;
    if (idx >= WTAP) return;
    int e = idx & 7, co = (idx >> 3) & 255, cig = (idx >> 11) & 31, tap = idx >> 16;
    int ci = cig * 8 + e;
    float v = w1[((size_t)co * CIN + ci) * 9 + tap];
    short h, l; splitbf(v, h, l);
    Wq[idx] = h; Wq[WTAP + idx] = l;
}

// ---------------- conv1 (3x3, 256->256) + BN + ReLU via MFMA bf16x3 ----------------
// grid (3 col-tiles, 45 row-tiles, 16 = b*4 + co-tile), block 256 (4 waves)
// block output: 64 co x (4 rows x 64 cols); wave: 16 co x 256 px (16 frags)
__global__ __launch_bounds__(256, 1)
void conv1_mfma(const float* __restrict__ in, const short* __restrict__ Wq,
                const float* __restrict__ gamma, const float* __restrict__ beta,
                const float* __restrict__ mean, const float* __restrict__ var,
                float* __restrict__ xout)
{
    __shared__ short Xs[2][2][6][66][40];   // [buf][hi/lo][row][col][ci-run pad 40] = 126.7 KB
    const int b  = blockIdx.z >> 2, co0 = (blockIdx.z & 3) * 64;
    const int y0 = blockIdx.y * 4, col0 = blockIdx.x * 64;
    const int tid  = threadIdx.x;
    const int w    = tid >> 6;
    const int lane = tid & 63;
    const int li = lane & 15, lg = lane >> 4;
    const short* Whi = Wq;
    const short* Wlo = Wq + WTAP;

    f32x4 acc[4][4];
    #pragma unroll
    for (int r = 0; r < 4; ++r)
        #pragma unroll
        for (int c = 0; c < 4; ++c) acc[r][c] = (f32x4){0.f, 0.f, 0.f, 0.f};

    // staging item geometry: 396 (row,col) items per ci-group slice; thread does <=2
    const int row_a = tid / 66, col_a = tid % 66;
    const int rc1   = tid + 256;
    const bool do_b = rc1 < 396;
    const int row_b = rc1 / 66, col_b = rc1 % 66;
    const int gy_a = y0 - 1 + row_a, gx_a = col0 - 1 + col_a;
    const int gy_b = y0 - 1 + row_b, gx_b = col0 - 1 + col_b;
    const bool val_a = ((unsigned)gy_a < (unsigned)H) && ((unsigned)gx_a < (unsigned)W);
    const bool val_b = do_b && ((unsigned)gy_b < (unsigned)H) && ((unsigned)gx_b < (unsigned)W);

    // ---- prologue: stage chunk 0 into buffer 0 ----
    #pragma unroll
    for (int cig = 0; cig < 4; ++cig) {
        const float* srcA = in + ((size_t)(b*CIN + cig*8) * H + gy_a) * W + gx_a;
        short h[8], l[8];
        #pragma unroll
        for (int e = 0; e < 8; ++e) {
            float v = val_a ? srcA[(size_t)e * HW] : 0.f;
            splitbf(v, h[e], l[e]);
        }
        short8 vh, vl;
        #pragma unroll
        for (int e = 0; e < 8; ++e) { vh[e] = h[e]; vl[e] = l[e]; }
        *(short8*)&Xs[0][0][row_a][col_a][cig*8] = vh;
        *(short8*)&Xs[0][1][row_a][col_a][cig*8] = vl;
        if (do_b) {
            const float* srcB = in + ((size_t)(b*CIN + cig*8) * H + gy_b) * W + gx_b;
            #pragma unroll
            for (int e = 0; e < 8; ++e) {
                float v = val_b ? srcB[(size_t)e * HW] : 0.f;
                splitbf(v, h[e], l[e]);
            }
            short8 vh1, vl1;
            #pragma unroll
            for (int e = 0; e < 8; ++e) { vh1[e] = h[e]; vl1[e] = l[e]; }
            *(short8*)&Xs[0][0][row_b][col_b][cig*8] = vh1;
            *(short8*)&Xs[0][1][row_b][col_b][cig*8] = vl1;
        }
    }
    __syncthreads();

    for (int kc = 0; kc < 8; ++kc) {
        const int cur = kc & 1, nxt = cur ^ 1;
        const bool more = (kc < 7);
        // A-frags for this chunk: 9 taps x hi/lo, lane holds co=co0+w*16+li, 8 ci
        short8 ah[9], al[9];
        {
            const int cig = kc * 4 + lg;
            const size_t base = ((size_t)cig * 256 + (co0 + w*16 + li)) * 8;
            #pragma unroll
            for (int t = 0; t < 9; ++t) {
                size_t off = (size_t)t * (32 * 256 * 8) + base;
                ah[t] = *(const short8*)(Whi + off);
                al[t] = *(const short8*)(Wlo + off);
            }
        }
        #pragma unroll
        for (int c16 = 0; c16 < 4; ++c16) {
            // issue staging loads for next chunk, ci-group slice = c16 (T14: early issue)
            float s0[8], s1[8];
            if (more) {
                const int cib = (kc + 1) * 32 + c16 * 8;
                const float* srcA = in + ((size_t)(b*CIN + cib) * H + gy_a) * W + gx_a;
                #pragma unroll
                for (int e = 0; e < 8; ++e) s0[e] = val_a ? srcA[(size_t)e * HW] : 0.f;
                const float* srcB = in + ((size_t)(b*CIN + cib) * H + gy_b) * W + gx_b;
                #pragma unroll
                for (int e = 0; e < 8; ++e) s1[e] = val_b ? srcB[(size_t)e * HW] : 0.f;
            }
            // MFMA: 3 dx x (12 B-frag reads + 3 dy x 4 r x 3 products)
            #pragma unroll
            for (int dx = 0; dx < 3; ++dx) {
                const int cc = c16 * 16 + li + dx;
                short8 bh[6], bl[6];
                #pragma unroll
                for (int rr = 0; rr < 6; ++rr) {
                    bh[rr] = *(const short8*)&Xs[cur][0][rr][cc][lg*8];
                    bl[rr] = *(const short8*)&Xs[cur][1][rr][cc][lg*8];
                }
                #pragma unroll
                for (int dy = 0; dy < 3; ++dy) {
                    const int t = dy * 3 + dx;
                    #pragma unroll
                    for (int r = 0; r < 4; ++r) {
                        f32x4 a = acc[r][c16];
                        a = __builtin_amdgcn_mfma_f32_16x16x32_bf16(ah[t], bh[r+dy], a, 0, 0, 0);
                        a = __builtin_amdgcn_mfma_f32_16x16x32_bf16(ah[t], bl[r+dy], a, 0, 0, 0);
                        a = __builtin_amdgcn_mfma_f32_16x16x32_bf16(al[t], bh[r+dy], a, 0, 0, 0);
                        acc[r][c16] = a;
                    }
                }
            }
            // write staged slice into next buffer
            if (more) {
                short h[8], l[8];
                #pragma unroll
                for (int e = 0; e < 8; ++e) splitbf(s0[e], h[e], l[e]);
                short8 vh, vl;
                #pragma unroll
                for (int e = 0; e < 8; ++e) { vh[e] = h[e]; vl[e] = l[e]; }
                *(short8*)&Xs[nxt][0][row_a][col_a][c16*8] = vh;
                *(short8*)&Xs[nxt][1][row_a][col_a][c16*8] = vl;
                if (do_b) {
                    #pragma unroll
                    for (int e = 0; e < 8; ++e) splitbf(s1[e], h[e], l[e]);
                    short8 vh1, vl1;
                    #pragma unroll
                    for (int e = 0; e < 8; ++e) { vh1[e] = h[e]; vl1[e] = l[e]; }
                    *(short8*)&Xs[nxt][0][row_b][col_b][c16*8] = vh1;
                    *(short8*)&Xs[nxt][1][row_b][col_b][c16*8] = vl1;
                }
            }
        }
        __syncthreads();
    }

    // epilogue: BN + ReLU + store (C layout: col=lane&15, row=(lane>>4)*4+q)
    float scv[4], shv[4];
    #pragma unroll
    for (int q = 0; q < 4; ++q) {
        int co = co0 + w*16 + lg*4 + q;
        float s = gamma[co] / sqrtf(var[co] + 1e-5f);
        scv[q] = s; shv[q] = beta[co] - mean[co] * s;
    }
    #pragma unroll
    for (int r = 0; r < 4; ++r) {
        #pragma unroll
        for (int c16 = 0; c16 < 4; ++c16) {
            int x = col0 + c16 * 16 + li;
            if (x < W) {
                #pragma unroll
                for (int q = 0; q < 4; ++q) {
                    int co = co0 + w*16 + lg*4 + q;
                    float v = fmaxf(fmaf(acc[r][c16][q], scv[q], shv[q]), 0.f);
                    xout[((size_t)(b*CIN + co) * H + (y0 + r)) * W + x] = v;
                }
            }
        }
    }
}

// ---------------- conv2 (3x3, 256->10) + bias ----------------
__global__ __launch_bounds__(256, 3)
void conv2_bias(const float* __restrict__ x, const float* __restrict__ wgt,
                const float* __restrict__ bias, float* __restrict__ dense)
{
    __shared__ float s_in[16][6][68];
    __shared__ float s_w[16][9][12];
    const int bx = blockIdx.x, by = blockIdx.y, b = blockIdx.z;
    const int row0 = by * 4, col0 = bx * 64;
    const int tid = threadIdx.x;
    const int trow = tid >> 6, j = tid & 63;
    float acc[10];
    #pragma unroll
    for (int k = 0; k < 10; ++k) acc[k] = 0.f;

    for (int ci0 = 0; ci0 < CIN; ci0 += 16) {
        __syncthreads();
        for (int l = tid; l < 16*6*66; l += 256) {
            int ci = l / 396, rem = l % 396;
            int r = rem / 66, c = rem % 66;
            int gy = row0 - 1 + r, gx = col0 - 1 + c;
            float v = 0.f;
            if ((unsigned)gy < (unsigned)H && (unsigned)gx < (unsigned)W)
                v = x[(((size_t)b*CIN + ci0 + ci)*H + gy)*W + gx];
            s_in[ci][r][c] = v;
        }
        for (int l = tid; l < 10*16*9; l += 256) {
            int co = l / 144, k = l % 144;
            int ci = k / 9, tap = k % 9;
            s_w[ci][tap][co] = wgt[((size_t)co*CIN + ci0 + ci)*9 + tap];
        }
        __syncthreads();
        #pragma unroll
        for (int ci = 0; ci < 16; ++ci) {
            #pragma unroll
            for (int dy = 0; dy < 3; ++dy) {
                float iv[3];
                #pragma unroll
                for (int t = 0; t < 3; ++t) iv[t] = s_in[ci][trow+dy][j + t];
                #pragma unroll
                for (int dx = 0; dx < 3; ++dx) {
                    const float* wp = &s_w[ci][dy*3+dx][0];
                    float4 wa = *(const float4*)wp;
                    float4 wb = *(const float4*)(wp + 4);
                    float2 wc = *(const float2*)(wp + 8);
                    float ival = iv[dx];
                    acc[0] = fmaf(wa.x, ival, acc[0]);
                    acc[1] = fmaf(wa.y, ival, acc[1]);
                    acc[2] = fmaf(wa.z, ival, acc[2]);
                    acc[3] = fmaf(wa.w, ival, acc[3]);
                    acc[4] = fmaf(wb.x, ival, acc[4]);
                    acc[5] = fmaf(wb.y, ival, acc[5]);
                    acc[6] = fmaf(wb.z, ival, acc[6]);
                    acc[7] = fmaf(wb.w, ival, acc[7]);
                    acc[8] = fmaf(wc.x, ival, acc[8]);
                    acc[9] = fmaf(wc.y, ival, acc[9]);
                }
            }
        }
    }
    const int y = row0 + trow, xcol = col0 + j;
    if (xcol < W) {
        #pragma unroll
        for (int k = 0; k < 10; ++k)
            dense[(((size_t)b*NCLS + k)*H + y)*W + xcol] = acc[k] + bias[k];
    }
}

// ---------------- sigmoid + 3x3 NMS ----------------
__global__ void nms_kernel(const float* __restrict__ dense, float* __restrict__ nms)
{
    const int x = threadIdx.x;
    if (x >= W) return;
    const int bk = blockIdx.x;
    const int y = blockIdx.y;
    const int k = bk % NCLS;
    const float* p = dense + (size_t)bk * HW;
    float c = sigm(p[y*W + x]);
    float outv;
    if (k >= 8) {
        outv = c;
    } else if (x == 0 || x == W-1 || y == 0 || y == H-1) {
        outv = 0.f;
    } else {
        float m = c;
        #pragma unroll
        for (int dy = -1; dy <= 1; ++dy)
            #pragma unroll
            for (int dx = -1; dx <= 1; ++dx) {
                if (dy == 0 && dx == 0) continue;
                m = fmaxf(m, sigm(p[(y+dy)*W + (x+dx)]));
            }
        outv = (c == m) ? c : 0.f;
    }
    nms[(size_t)bk * HW + y*W + x] = outv;
}

// ---------------- histogram / scan / collect / sort / gather ----------------
__global__ void hist_kernel(const float* __restrict__ nms, int* __restrict__ hist)
{
    __shared__ int h[4096];
    const int b = blockIdx.y;
    for (int l = threadIdx.x; l < 4096; l += 256) h[l] = 0;
    __syncthreads();
    const float* p = nms + (size_t)b * (NCLS*HW);
    for (int i = blockIdx.x*256 + threadIdx.x; i < NCLS*HW; i += gridDim.x*256) {
        float v = p[i];
        if (v > 0.f) {
            int bin = (int)(v * 4096.f);
            if (bin > 4095) bin = 4095;
            atomicAdd(&h[bin], 1);
        }
    }
    __syncthreads();
    for (int l = threadIdx.x; l < 4096; l += 256)
        if (h[l]) atomicAdd(&hist[b*4096 + l], h[l]);
}

__global__ void scan_kernel(const int* __restrict__ hist, int* __restrict__ bsel)
{
    __shared__ int ss[256];
    const int b = blockIdx.x;
    const int t = threadIdx.x;
    const int base = 4096 - 16*(t+1);
    int s = 0;
    #pragma unroll
    for (int i = 0; i < 16; ++i) s += hist[b*4096 + base + i];
    ss[t] = s;
    __syncthreads();
    for (int off = 1; off < 256; off <<= 1) {
        int v = (t >= off) ? ss[t-off] : 0;
        __syncthreads();
        ss[t] += v;
        __syncthreads();
    }
    int incl = ss[t];
    int excl = incl - s;
    if (excl < NPROP && incl >= NPROP) {
        int acc2 = excl, bfound = base;
        for (int bin = base + 15; bin >= base; --bin) {
            acc2 += hist[b*4096 + bin];
            if (acc2 >= NPROP) { bfound = bin; break; }
        }
        bsel[b] = bfound;
    }
    if (t == 255 && ss[255] < NPROP) bsel[b] = 0;
}

__global__ void collect_kernel(const float* __restrict__ nms, const int* __restrict__ bsel,
                               int* __restrict__ cnt, unsigned long long* __restrict__ cand)
{
    const int b = blockIdx.y;
    const int B0 = bsel[b];
    const float* p = nms + (size_t)b * (NCLS*HW);
    for (int i = blockIdx.x*256 + threadIdx.x; i < NCLS*HW; i += gridDim.x*256) {
        float v = p[i];
        if (v > 0.f) {
            int bin = (int)(v * 4096.f);
            if (bin > 4095) bin = 4095;
            if (bin >= B0) {
                int slot = atomicAdd(&cnt[b], 1);
                if (slot < 4096) {
                    unsigned int vb = __float_as_uint(v);
                    cand[(size_t)b*4096 + slot] =
                        ((unsigned long long)(~vb) << 32) | (unsigned int)i;
                }
            }
        }
    }
}

__global__ void sort_emit(const unsigned long long* __restrict__ cand, const int* __restrict__ cnt,
                          const float* __restrict__ nms, const float* __restrict__ bev_pos,
                          float* __restrict__ out, int* __restrict__ tpos, int* __restrict__ tlab)
{
    __shared__ unsigned long long key[4096];
    const int b = blockIdx.x;
    const int t = threadIdx.x;
    int n = cnt[b]; if (n > 4096) n = 4096;
    for (int l = t; l < 4096; l += 1024)
        key[l] = (l < n) ? cand[(size_t)b*4096 + l] : ~0ULL;
    __syncthreads();
    for (int k = 2; k <= 4096; k <<= 1) {
        for (int jj = k >> 1; jj > 0; jj >>= 1) {
            for (int l = t; l < 2048; l += 1024) {
                int i  = 2*l - (l & (jj-1));
                int ix = i + jj;
                bool up = ((i & k) == 0);
                unsigned long long a = key[i], c = key[ix];
                if ((a > c) == up) { key[i] = c; key[ix] = a; }
            }
            __syncthreads();
        }
    }
    for (int p = t; p < NPROP; p += 1024) {
        unsigned long long kk = key[p];
        unsigned int idx = (unsigned int)kk;
        if (idx >= (unsigned)(NCLS*HW)) idx = 0;
        int label = idx / HW;
        int pos   = idx % HW;
        out[206400 + b*NPROP + p] = (float)label;
        out[204800 + (b*NPROP + p)*2 + 0] = bev_pos[pos*2 + 0];
        out[204800 + (b*NPROP + p)*2 + 1] = bev_pos[pos*2 + 1];
        tpos[b*NPROP + p] = pos;
        tlab[b*NPROP + p] = label;
        #pragma unroll
        for (int k2 = 0; k2 < NCLS; ++k2)
            out[207200 + (b*NCLS + k2)*NPROP + p] = nms[((size_t)b*NCLS + k2)*HW + pos];
    }
}

__global__ void feat_kernel(const float* __restrict__ bev, const float* __restrict__ cew,
                            const float* __restrict__ ceb, const int* __restrict__ tpos,
                            const int* __restrict__ tlab, float* __restrict__ out)
{
    const int c = blockIdx.x, b = blockIdx.y;
    const int t = threadIdx.x;
    if (t >= NPROP) return;
    int pos = tpos[b*NPROP + t];
    int lab = tlab[b*NPROP + t];
    float v = bev[((size_t)b*CIN + c)*HW + pos] + cew[c*NCLS + lab] + ceb[c];
    out[((size_t)b*CIN + c)*NPROP + t] = v;
}

extern "C" void kernel_launch(void* const* d_in, const int* in_sizes, int n_in,
                              void* d_out, int out_size, void* d_ws, size_t ws_size,
                              hipStream_t stream)
{
    const float* bev   = (const float*)d_in[0];
    const float* bpos  = (const float*)d_in[1];
    const float* w1    = (const float*)d_in[2];
    const float* gamma = (const float*)d_in[3];
    const float* beta  = (const float*)d_in[4];
    const float* mean  = (const float*)d_in[5];
    const float* var   = (const float*)d_in[6];
    const float* w2    = (const float*)d_in[7];
    const float* b2    = (const float*)d_in[8];
    const float* cew   = (const float*)d_in[9];
    const float* ceb   = (const float*)d_in[10];
    float* out = (float*)d_out;
    char* ws = (char*)d_ws;

    float* xbuf = (float*)(ws + OFF_X);
    float* nmsb = (float*)(ws + OFF_NMS);
    int* hist   = (int*)(ws + OFF_HIST);
    int* cnt    = (int*)(ws + OFF_CNT);
    unsigned long long* cand = (unsigned long long*)(ws + OFF_CAND);
    int* bsel   = (int*)(ws + OFF_BSEL);
    int* tpos   = (int*)(ws + OFF_TPOS);
    int* tlab   = (int*)(ws + OFF_TLAB);
    float* dense = out + 215200;
    // split weights alias the dense_heatmap region until conv2 overwrites it
    short* Wq = (short*)(out + 215200);

    split_w_kernel<<<(WTAP + 255)/256, 256, 0, stream>>>(w1, Wq);
    conv1_mfma<<<dim3(3, 45, 16), 256, 0, stream>>>(bev, Wq, gamma, beta, mean, var, xbuf);
    conv2_bias<<<dim3(3, 45, 4), 256, 0, stream>>>(xbuf, w2, b2, dense);
    hipMemsetAsync(ws + OFF_HIST, 0, 65536 + 32, stream);
    nms_kernel  <<<dim3(40, 180),   192, 0, stream>>>(dense, nmsb);
    hist_kernel <<<dim3(32, 4),     256, 0, stream>>>(nmsb, hist);
    scan_kernel <<<4,               256, 0, stream>>>(hist, bsel);
    collect_kernel<<<dim3(64, 4),   256, 0, stream>>>(nmsb, bsel, cnt, cand);
    sort_emit   <<<4,              1024, 0, stream>>>(cand, cnt, nmsb, bpos, out, tpos, tlab);
    feat_kernel <<<dim3(256, 4),    256, 0, stream>>>(bev, cew, ceb, tpos, tlab, out);
}

// Round 4
// 778.848 us; speedup vs baseline: 5.1191x; 1.4188x over previous
//
#include <hip/hip_runtime.h>
#include <hip/hip_bf16.h>
#include <stdint.h>

#define H 180
#define W 180
#define HW 32400
#define CIN 256
#define NCLS 10
#define NPROP 200
#define WTAP 589824    // 9 taps * 32 cig * 256 co * 8 = elems per split-weight variant
#define WTAP2 36864    // 9 taps * 32 cig * 16 co * 8 (conv2, co zero-padded 10->16)

// ---- workspace layout ----
// Phase 1 (conv1 -> conv2): x buffer owns [0, 132,710,400).
// Phase 2 (post-conv2): x dead; small buffers alias into it. ws need = 132.7 MB.
#define OFF_X      0ULL
#define OFF_NMS    0ULL
#define OFF_HIST   5184000ULL
#define OFF_CNT    5249536ULL
#define OFF_CAND   5249568ULL
#define OFF_BSEL   5380640ULL
#define OFF_TPOS   5380672ULL
#define OFF_TLAB   5383872ULL

typedef __attribute__((ext_vector_type(8))) short short8;
typedef __attribute__((ext_vector_type(4))) float f32x4;

__device__ __forceinline__ float sigm(float v) { return 1.0f / (1.0f + expf(-v)); }

__device__ __forceinline__ unsigned bfround(unsigned u) {
    return (u + 0x7FFFu + ((u >> 16) & 1u)) >> 16;
}
__device__ __forceinline__ void splitbf(float v, short &hi, short &lo) {
    unsigned u = __float_as_uint(v);
    unsigned hb = bfround(u);
    float fh = __uint_as_float(hb << 16);
    unsigned lb = bfround(__float_as_uint(v - fh));
    hi = (short)hb; lo = (short)lb;
}

// ---------------- weight split/reorder: OIHW f32 -> [tap][ci/8][co][8] bf16 hi|lo ----
__global__ void split_w_kernel(const float* __restrict__ w1, short* __restrict__ Wq)
{
    int idx = blockIdx.x * 256 + threadIdx.x;
    if (idx >= WTAP) return;
    int e = idx & 7, co = (idx >> 3) & 255, cig = (idx >> 11) & 31, tap = idx >> 16;
    int ci = cig * 8 + e;
    float v = w1[((size_t)co * CIN + ci) * 9 + tap];
    short h, l; splitbf(v, h, l);
    Wq[idx] = h; Wq[WTAP + idx] = l;
}

// conv2 weights: [10][256][9] f32 -> [tap][cig][co16][8] bf16 hi|lo (co 10..15 zero)
__global__ void split_w2_kernel(const float* __restrict__ w2, short* __restrict__ Wq2)
{
    int idx = blockIdx.x * 256 + threadIdx.x;
    if (idx >= WTAP2) return;
    int e = idx & 7, co = (idx >> 3) & 15, cig = (idx >> 7) & 31, tap = idx >> 12;
    int ci = cig * 8 + e;
    float v = (co < NCLS) ? w2[((size_t)co * CIN + ci) * 9 + tap] : 0.f;
    short h, l; splitbf(v, h, l);
    Wq2[idx] = h; Wq2[WTAP2 + idx] = l;
}

// ---------------- conv1 (3x3, 256->256) + BN + ReLU via MFMA bf16x3 ----------------
// grid (6 col-tiles, 45 row-tiles, 8 = b*2 + cogroup), block 256 (4 waves)
// block out: 128 co x (4 rows x 32 cols); wave: 32 co (2 tiles) x 4r x 2 c16
__global__ __launch_bounds__(256, 2)
void conv1_mfma(const float* __restrict__ in, const short* __restrict__ Wq,
                const float* __restrict__ gamma, const float* __restrict__ beta,
                const float* __restrict__ mean, const float* __restrict__ var,
                float* __restrict__ xout)
{
    __shared__ short Xs[2][2][6][34][36];   // [buf][hi/lo][row][col][ci pad36] = 58,752 B
    const int b    = blockIdx.z >> 1;
    const int co0  = (blockIdx.z & 1) * 128;
    const int y0   = blockIdx.y * 4;
    const int col0 = blockIdx.x * 32;
    const int tid  = threadIdx.x;
    const int w    = tid >> 6;
    const int lane = tid & 63;
    const int li = lane & 15, lg = lane >> 4;
    const int cobase = co0 + w * 32;

    f32x4 acc[2][4][2];   // [co-tile][r][c16]
    #pragma unroll
    for (int ct = 0; ct < 2; ++ct)
        #pragma unroll
        for (int r = 0; r < 4; ++r)
            #pragma unroll
            for (int c = 0; c < 2; ++c) acc[ct][r][c] = (f32x4){0.f,0.f,0.f,0.f};

    // staging decode: item-slices 0..815 (= 4 ci-slices x 6 rows x 34 cols)
    int sl_[4], rr_[4], cc_[4];
    bool va_[4], inb_[4];
    const float* src_[4];
    #pragma unroll
    for (int it = 0; it < 4; ++it) {
        int is = tid + it * 256;
        bool va = is < 816;
        int isc = va ? is : 0;
        int sl = isc / 204, rem = isc % 204;
        int r = rem / 34, c = rem % 34;
        int gy = y0 - 1 + r, gx = col0 - 1 + c;
        bool inb = va && ((unsigned)gy < (unsigned)H) && ((unsigned)gx < (unsigned)W);
        sl_[it]=sl; rr_[it]=r; cc_[it]=c; va_[it]=va; inb_[it]=inb;
        src_[it] = in + ((size_t)(b*CIN + sl*8) * H + gy) * W + gx;
    }

    float sA[4][8];
    // ---- prologue: load + write chunk 0 ----
    #pragma unroll
    for (int it = 0; it < 4; ++it)
        #pragma unroll
        for (int e = 0; e < 8; ++e)
            sA[it][e] = inb_[it] ? src_[it][(size_t)e * HW] : 0.f;
    #pragma unroll
    for (int it = 0; it < 4; ++it) {
        if (va_[it]) {
            short h[8], l[8];
            #pragma unroll
            for (int e = 0; e < 8; ++e) splitbf(sA[it][e], h[e], l[e]);
            short8 vh, vl;
            #pragma unroll
            for (int e = 0; e < 8; ++e) { vh[e] = h[e]; vl[e] = l[e]; }
            *(short8*)&Xs[0][0][rr_[it]][cc_[it]][sl_[it]*8] = vh;
            *(short8*)&Xs[0][1][rr_[it]][cc_[it]][sl_[it]*8] = vl;
        }
    }
    __syncthreads();

    for (int kc = 0; kc < 8; ++kc) {
        const int cur = kc & 1, nxt = cur ^ 1;
        const bool more = (kc < 7);
        // T14: issue next chunk's global loads before compute
        if (more) {
            const size_t coff = (size_t)(kc + 1) * 32 * HW;
            #pragma unroll
            for (int it = 0; it < 4; ++it)
                #pragma unroll
                for (int e = 0; e < 8; ++e)
                    sA[it][e] = inb_[it] ? src_[it][coff + (size_t)e * HW] : 0.f;
        }
        // compute chunk kc
        const int cig = kc * 4 + lg;
        const short* pA = Wq + ((size_t)cig * 256 + cobase + li) * 8;
        #pragma unroll
        for (int dx = 0; dx < 3; ++dx) {
            short8 a_h[3][2], a_l[3][2];
            #pragma unroll
            for (int dy = 0; dy < 3; ++dy) {
                const int off = (dy*3 + dx) * 65536;
                a_h[dy][0] = *(const short8*)(pA + off);
                a_h[dy][1] = *(const short8*)(pA + off + 128);
                a_l[dy][0] = *(const short8*)(pA + WTAP + off);
                a_l[dy][1] = *(const short8*)(pA + WTAP + off + 128);
            }
            #pragma unroll
            for (int c16 = 0; c16 < 2; ++c16) {
                const int ccol = c16 * 16 + li + dx;
                short8 bh[6], bl[6];
                #pragma unroll
                for (int rr = 0; rr < 6; ++rr) {
                    bh[rr] = *(const short8*)&Xs[cur][0][rr][ccol][lg*8];
                    bl[rr] = *(const short8*)&Xs[cur][1][rr][ccol][lg*8];
                }
                #pragma unroll
                for (int dy = 0; dy < 3; ++dy) {
                    #pragma unroll
                    for (int r = 0; r < 4; ++r) {
                        #pragma unroll
                        for (int ct = 0; ct < 2; ++ct) {
                            f32x4 a = acc[ct][r][c16];
                            a = __builtin_amdgcn_mfma_f32_16x16x32_bf16(a_h[dy][ct], bh[r+dy], a, 0, 0, 0);
                            a = __builtin_amdgcn_mfma_f32_16x16x32_bf16(a_h[dy][ct], bl[r+dy], a, 0, 0, 0);
                            a = __builtin_amdgcn_mfma_f32_16x16x32_bf16(a_l[dy][ct], bh[r+dy], a, 0, 0, 0);
                            acc[ct][r][c16] = a;
                        }
                    }
                }
            }
        }
        // write next chunk into other buffer (safe: nxt's readers done last barrier)
        if (more) {
            #pragma unroll
            for (int it = 0; it < 4; ++it) {
                if (va_[it]) {
                    short h[8], l[8];
                    #pragma unroll
                    for (int e = 0; e < 8; ++e) splitbf(sA[it][e], h[e], l[e]);
                    short8 vh, vl;
                    #pragma unroll
                    for (int e = 0; e < 8; ++e) { vh[e] = h[e]; vl[e] = l[e]; }
                    *(short8*)&Xs[nxt][0][rr_[it]][cc_[it]][sl_[it]*8] = vh;
                    *(short8*)&Xs[nxt][1][rr_[it]][cc_[it]][sl_[it]*8] = vl;
                }
            }
        }
        __syncthreads();
    }

    // epilogue: BN + ReLU + store (C layout: col=lane&15, row=(lane>>4)*4+q)
    #pragma unroll
    for (int ct = 0; ct < 2; ++ct) {
        float scv[4], shv[4];
        #pragma unroll
        for (int q = 0; q < 4; ++q) {
            int co = cobase + ct*16 + lg*4 + q;
            float s = gamma[co] / sqrtf(var[co] + 1e-5f);
            scv[q] = s; shv[q] = beta[co] - mean[co] * s;
        }
        #pragma unroll
        for (int r = 0; r < 4; ++r) {
            #pragma unroll
            for (int c16 = 0; c16 < 2; ++c16) {
                int x = col0 + c16*16 + li;
                if (x < W) {
                    #pragma unroll
                    for (int q = 0; q < 4; ++q) {
                        int co = cobase + ct*16 + lg*4 + q;
                        float v = fmaxf(fmaf(acc[ct][r][c16][q], scv[q], shv[q]), 0.f);
                        xout[((size_t)(b*CIN + co) * H + (y0 + r)) * W + x] = v;
                    }
                }
            }
        }
    }
}

// ---------------- conv2 (3x3, 256->10) + bias via MFMA bf16x3 ----------------
// grid (6, 45, 4=b), block 256 (4 waves)
// block out: 16co(10 used) x 4 rows x 32 cols; wave: c16 = w&1, row-half = w>>1
__global__ __launch_bounds__(256, 2)
void conv2_mfma(const float* __restrict__ x, const short* __restrict__ Wq2,
                const float* __restrict__ bias, float* __restrict__ dense)
{
    __shared__ short Xs[2][2][6][34][36];
    const int b    = blockIdx.z;
    const int y0   = blockIdx.y * 4;
    const int col0 = blockIdx.x * 32;
    const int tid  = threadIdx.x;
    const int w    = tid >> 6;
    const int lane = tid & 63;
    const int li = lane & 15, lg = lane >> 4;
    const int c16w = w & 1, rh = w >> 1;

    f32x4 acc2[2];
    acc2[0] = (f32x4){0.f,0.f,0.f,0.f};
    acc2[1] = (f32x4){0.f,0.f,0.f,0.f};

    int sl_[4], rr_[4], cc_[4];
    bool va_[4], inb_[4];
    const float* src_[4];
    #pragma unroll
    for (int it = 0; it < 4; ++it) {
        int is = tid + it * 256;
        bool va = is < 816;
        int isc = va ? is : 0;
        int sl = isc / 204, rem = isc % 204;
        int r = rem / 34, c = rem % 34;
        int gy = y0 - 1 + r, gx = col0 - 1 + c;
        bool inb = va && ((unsigned)gy < (unsigned)H) && ((unsigned)gx < (unsigned)W);
        sl_[it]=sl; rr_[it]=r; cc_[it]=c; va_[it]=va; inb_[it]=inb;
        src_[it] = x + ((size_t)(b*CIN + sl*8) * H + gy) * W + gx;
    }

    float sA[4][8];
    #pragma unroll
    for (int it = 0; it < 4; ++it)
        #pragma unroll
        for (int e = 0; e < 8; ++e)
            sA[it][e] = inb_[it] ? src_[it][(size_t)e * HW] : 0.f;
    #pragma unroll
    for (int it = 0; it < 4; ++it) {
        if (va_[it]) {
            short h[8], l[8];
            #pragma unroll
            for (int e = 0; e < 8; ++e) splitbf(sA[it][e], h[e], l[e]);
            short8 vh, vl;
            #pragma unroll
            for (int e = 0; e < 8; ++e) { vh[e] = h[e]; vl[e] = l[e]; }
            *(short8*)&Xs[0][0][rr_[it]][cc_[it]][sl_[it]*8] = vh;
            *(short8*)&Xs[0][1][rr_[it]][cc_[it]][sl_[it]*8] = vl;
        }
    }
    __syncthreads();

    for (int kc = 0; kc < 8; ++kc) {
        const int cur = kc & 1, nxt = cur ^ 1;
        const bool more = (kc < 7);
        if (more) {
            const size_t coff = (size_t)(kc + 1) * 32 * HW;
            #pragma unroll
            for (int it = 0; it < 4; ++it)
                #pragma unroll
                for (int e = 0; e < 8; ++e)
                    sA[it][e] = inb_[it] ? src_[it][coff + (size_t)e * HW] : 0.f;
        }
        const int cig = kc * 4 + lg;
        const short* pA = Wq2 + ((size_t)cig * 16 + li) * 8;
        #pragma unroll
        for (int dx = 0; dx < 3; ++dx) {
            short8 a_h[3], a_l[3];
            #pragma unroll
            for (int dy = 0; dy < 3; ++dy) {
                const int off = (dy*3 + dx) * 4096;
                a_h[dy] = *(const short8*)(pA + off);
                a_l[dy] = *(const short8*)(pA + WTAP2 + off);
            }
            const int ccol = c16w * 16 + li + dx;
            short8 bh[4], bl[4];
            #pragma unroll
            for (int rr = 0; rr < 4; ++rr) {
                bh[rr] = *(const short8*)&Xs[cur][0][rh*2 + rr][ccol][lg*8];
                bl[rr] = *(const short8*)&Xs[cur][1][rh*2 + rr][ccol][lg*8];
            }
            #pragma unroll
            for (int dy = 0; dy < 3; ++dy) {
                #pragma unroll
                for (int r2 = 0; r2 < 2; ++r2) {
                    f32x4 a = acc2[r2];
                    a = __builtin_amdgcn_mfma_f32_16x16x32_bf16(a_h[dy], bh[r2+dy], a, 0, 0, 0);
                    a = __builtin_amdgcn_mfma_f32_16x16x32_bf16(a_h[dy], bl[r2+dy], a, 0, 0, 0);
                    a = __builtin_amdgcn_mfma_f32_16x16x32_bf16(a_l[dy], bh[r2+dy], a, 0, 0, 0);
                    acc2[r2] = a;
                }
            }
        }
        if (more) {
            #pragma unroll
            for (int it = 0; it < 4; ++it) {
                if (va_[it]) {
                    short h[8], l[8];
                    #pragma unroll
                    for (int e = 0; e < 8; ++e) splitbf(sA[it][e], h[e], l[e]);
                    short8 vh, vl;
                    #pragma unroll
                    for (int e = 0; e < 8; ++e) { vh[e] = h[e]; vl[e] = l[e]; }
                    *(short8*)&Xs[nxt][0][rr_[it]][cc_[it]][sl_[it]*8] = vh;
                    *(short8*)&Xs[nxt][1][rr_[it]][cc_[it]][sl_[it]*8] = vl;
                }
            }
        }
        __syncthreads();
    }

    #pragma unroll
    for (int r2 = 0; r2 < 2; ++r2) {
        const int y = y0 + rh*2 + r2;
        const int xc = col0 + c16w*16 + li;
        if (xc < W) {
            #pragma unroll
            for (int q = 0; q < 4; ++q) {
                int co = lg*4 + q;
                if (co < NCLS)
                    dense[((size_t)(b*NCLS + co) * H + y) * W + xc] = acc2[r2][q] + bias[co];
            }
        }
    }
}

// ---------------- sigmoid + 3x3 NMS ----------------
__global__ void nms_kernel(const float* __restrict__ dense, float* __restrict__ nms)
{
    const int x = threadIdx.x;
    if (x >= W) return;
    const int bk = blockIdx.x;
    const int y = blockIdx.y;
    const int k = bk % NCLS;
    const float* p = dense + (size_t)bk * HW;
    float c = sigm(p[y*W + x]);
    float outv;
    if (k >= 8) {
        outv = c;
    } else if (x == 0 || x == W-1 || y == 0 || y == H-1) {
        outv = 0.f;
    } else {
        float m = c;
        #pragma unroll
        for (int dy = -1; dy <= 1; ++dy)
            #pragma unroll
            for (int dx = -1; dx <= 1; ++dx) {
                if (dy == 0 && dx == 0) continue;
                m = fmaxf(m, sigm(p[(y+dy)*W + (x+dx)]));
            }
        outv = (c == m) ? c : 0.f;
    }
    nms[(size_t)bk * HW + y*W + x] = outv;
}

// ---------------- histogram / scan / collect / sort / gather ----------------
__global__ void hist_kernel(const float* __restrict__ nms, int* __restrict__ hist)
{
    __shared__ int h[4096];
    const int b = blockIdx.y;
    for (int l = threadIdx.x; l < 4096; l += 256) h[l] = 0;
    __syncthreads();
    const float* p = nms + (size_t)b * (NCLS*HW);
    for (int i = blockIdx.x*256 + threadIdx.x; i < NCLS*HW; i += gridDim.x*256) {
        float v = p[i];
        if (v > 0.f) {
            int bin = (int)(v * 4096.f);
            if (bin > 4095) bin = 4095;
            atomicAdd(&h[bin], 1);
        }
    }
    __syncthreads();
    for (int l = threadIdx.x; l < 4096; l += 256)
        if (h[l]) atomicAdd(&hist[b*4096 + l], h[l]);
}

__global__ void scan_kernel(const int* __restrict__ hist, int* __restrict__ bsel)
{
    __shared__ int ss[256];
    const int b = blockIdx.x;
    const int t = threadIdx.x;
    const int base = 4096 - 16*(t+1);
    int s = 0;
    #pragma unroll
    for (int i = 0; i < 16; ++i) s += hist[b*4096 + base + i];
    ss[t] = s;
    __syncthreads();
    for (int off = 1; off < 256; off <<= 1) {
        int v = (t >= off) ? ss[t-off] : 0;
        __syncthreads();
        ss[t] += v;
        __syncthreads();
    }
    int incl = ss[t];
    int excl = incl - s;
    if (excl < NPROP && incl >= NPROP) {
        int acc2 = excl, bfound = base;
        for (int bin = base + 15; bin >= base; --bin) {
            acc2 += hist[b*4096 + bin];
            if (acc2 >= NPROP) { bfound = bin; break; }
        }
        bsel[b] = bfound;
    }
    if (t == 255 && ss[255] < NPROP) bsel[b] = 0;
}

__global__ void collect_kernel(const float* __restrict__ nms, const int* __restrict__ bsel,
                               int* __restrict__ cnt, unsigned long long* __restrict__ cand)
{
    const int b = blockIdx.y;
    const int B0 = bsel[b];
    const float* p = nms + (size_t)b * (NCLS*HW);
    for (int i = blockIdx.x*256 + threadIdx.x; i < NCLS*HW; i += gridDim.x*256) {
        float v = p[i];
        if (v > 0.f) {
            int bin = (int)(v * 4096.f);
            if (bin > 4095) bin = 4095;
            if (bin >= B0) {
                int slot = atomicAdd(&cnt[b], 1);
                if (slot < 4096) {
                    unsigned int vb = __float_as_uint(v);
                    cand[(size_t)b*4096 + slot] =
                        ((unsigned long long)(~vb) << 32) | (unsigned int)i;
                }
            }
        }
    }
}

__global__ void sort_emit(const unsigned long long* __restrict__ cand, const int* __restrict__ cnt,
                          const float* __restrict__ nms, const float* __restrict__ bev_pos,
                          float* __restrict__ out, int* __restrict__ tpos, int* __restrict__ tlab)
{
    __shared__ unsigned long long key[4096];
    const int b = blockIdx.x;
    const int t = threadIdx.x;
    int n = cnt[b]; if (n > 4096) n = 4096;
    for (int l = t; l < 4096; l += 1024)
        key[l] = (l < n) ? cand[(size_t)b*4096 + l] : ~0ULL;
    __syncthreads();
    for (int k = 2; k <= 4096; k <<= 1) {
        for (int jj = k >> 1; jj > 0; jj >>= 1) {
            for (int l = t; l < 2048; l += 1024) {
                int i  = 2*l - (l & (jj-1));
                int ix = i + jj;
                bool up = ((i & k) == 0);
                unsigned long long a = key[i], c = key[ix];
                if ((a > c) == up) { key[i] = c; key[ix] = a; }
            }
            __syncthreads();
        }
    }
    for (int p = t; p < NPROP; p += 1024) {
        unsigned long long kk = key[p];
        unsigned int idx = (unsigned int)kk;
        if (idx >= (unsigned)(NCLS*HW)) idx = 0;
        int label = idx / HW;
        int pos   = idx % HW;
        out[206400 + b*NPROP + p] = (float)label;
        out[204800 + (b*NPROP + p)*2 + 0] = bev_pos[pos*2 + 0];
        out[204800 + (b*NPROP + p)*2 + 1] = bev_pos[pos*2 + 1];
        tpos[b*NPROP + p] = pos;
        tlab[b*NPROP + p] = label;
        #pragma unroll
        for (int k2 = 0; k2 < NCLS; ++k2)
            out[207200 + (b*NCLS + k2)*NPROP + p] = nms[((size_t)b*NCLS + k2)*HW + pos];
    }
}

__global__ void feat_kernel(const float* __restrict__ bev, const float* __restrict__ cew,
                            const float* __restrict__ ceb, const int* __restrict__ tpos,
                            const int* __restrict__ tlab, float* __restrict__ out)
{
    const int c = blockIdx.x, b = blockIdx.y;
    const int t = threadIdx.x;
    if (t >= NPROP) return;
    int pos = tpos[b*NPROP + t];
    int lab = tlab[b*NPROP + t];
    float v = bev[((size_t)b*CIN + c)*HW + pos] + cew[c*NCLS + lab] + ceb[c];
    out[((size_t)b*CIN + c)*NPROP + t] = v;
}

extern "C" void kernel_launch(void* const* d_in, const int* in_sizes, int n_in,
                              void* d_out, int out_size, void* d_ws, size_t ws_size,
                              hipStream_t stream)
{
    const float* bev   = (const float*)d_in[0];
    const float* bpos  = (const float*)d_in[1];
    const float* w1    = (const float*)d_in[2];
    const float* gamma = (const float*)d_in[3];
    const float* beta  = (const float*)d_in[4];
    const float* mean  = (const float*)d_in[5];
    const float* var   = (const float*)d_in[6];
    const float* w2    = (const float*)d_in[7];
    const float* b2    = (const float*)d_in[8];
    const float* cew   = (const float*)d_in[9];
    const float* ceb   = (const float*)d_in[10];
    float* out = (float*)d_out;
    char* ws = (char*)d_ws;

    float* xbuf = (float*)(ws + OFF_X);
    float* nmsb = (float*)(ws + OFF_NMS);
    int* hist   = (int*)(ws + OFF_HIST);
    int* cnt    = (int*)(ws + OFF_CNT);
    unsigned long long* cand = (unsigned long long*)(ws + OFF_CAND);
    int* bsel   = (int*)(ws + OFF_BSEL);
    int* tpos   = (int*)(ws + OFF_TPOS);
    int* tlab   = (int*)(ws + OFF_TLAB);
    float* dense = out + 215200;
    // Wq1 aliases the dense region (conv1 reads it before conv2 writes dense).
    // Wq2 aliases out[0..) (query_feat region, overwritten by feat_kernel at the end).
    short* Wq  = (short*)(out + 215200);
    short* Wq2 = (short*)out;

    split_w_kernel <<<(WTAP  + 255)/256, 256, 0, stream>>>(w1, Wq);
    split_w2_kernel<<<(WTAP2 + 255)/256, 256, 0, stream>>>(w2, Wq2);
    conv1_mfma<<<dim3(6, 45, 8), 256, 0, stream>>>(bev, Wq, gamma, beta, mean, var, xbuf);
    conv2_mfma<<<dim3(6, 45, 4), 256, 0, stream>>>(xbuf, Wq2, b2, dense);
    hipMemsetAsync(ws + OFF_HIST, 0, 65536 + 32, stream);
    nms_kernel  <<<dim3(40, 180),   192, 0, stream>>>(dense, nmsb);
    hist_kernel <<<dim3(32, 4),     256, 0, stream>>>(nmsb, hist);
    scan_kernel <<<4,               256, 0, stream>>>(hist, bsel);
    collect_kernel<<<dim3(64, 4),   256, 0, stream>>>(nmsb, bsel, cnt, cand);
    sort_emit   <<<4,              1024, 0, stream>>>(cand, cnt, nmsb, bpos, out, tpos, tlab);
    feat_kernel <<<dim3(256, 4),    256, 0, stream>>>(bev, cew, ceb, tpos, tlab, out);
}